// Round 2
// baseline (475.499 us; speedup 1.0000x reference)
//
#include <hip/hip_runtime.h>
#include <hip/hip_bf16.h>

#define NN   50000
#define EE   800000
#define INF_ 128
#define HH   16
#define OUTC 300

__device__ __forceinline__ float bfu2f(unsigned short u) {
    return __uint_as_float(((unsigned)u) << 16);
}

// ---- dtype detect: scan low-half-bf16 of first 256 words of x.
// fp32 data -> low halves are mantissa garbage, ~45% huge/NaN. bf16 data -> real values, 0 hits.
__global__ __launch_bounds__(64) void detect_kernel(const unsigned* __restrict__ xw, int* __restrict__ flag) {
    int t = threadIdx.x;
    int hits = 0;
#pragma unroll
    for (int q = 0; q < 4; q++) {
        unsigned w = xw[t * 4 + q];
        float lo = __uint_as_float(w << 16);
        if (!(fabsf(lo) < 1e4f)) hits++;   // also catches NaN/inf
    }
#pragma unroll
    for (int o = 32; o > 0; o >>= 1) hits += __shfl_xor(hits, o);
    if (t == 0) flag[0] = (hits > 8) ? 1 : 0;   // 1 => inputs are fp32
}

// ---- degree: deg[d] += 1 per incoming edge ----
__global__ __launch_bounds__(256) void deg_kernel(const int* __restrict__ dst, float* __restrict__ deg) {
    int e = blockIdx.x * 256 + threadIdx.x;
    if (e < EE) atomicAdd(&deg[dst[e]], 1.0f);
}

// ---- dinv[i] = rsqrt(deg[i] + 1) in place ----
__global__ __launch_bounds__(256) void dinv_kernel(float* __restrict__ deg) {
    int i = blockIdx.x * 256 + threadIdx.x;
    if (i < NN) deg[i] = rsqrtf(deg[i] + 1.0f);
}

// ---- layer1 linear: A = (x@W1)*dinv, B = x@Wl1 + bl1 ----
__global__ __launch_bounds__(256) void lin1_kernel(
    const void* __restrict__ xp, const void* __restrict__ W1p,
    const void* __restrict__ Wl1p, const void* __restrict__ bl1p,
    const float* __restrict__ dinv, const int* __restrict__ flagp,
    float* __restrict__ A, float* __restrict__ B)
{
    __shared__ float sW[INF_ * HH];
    __shared__ float sL[INF_ * HH];
    __shared__ float sb[HH];
    const int flag = flagp[0];
    if (flag) {
        const float* W1f  = (const float*)W1p;
        const float* Wl1f = (const float*)Wl1p;
        for (int t = threadIdx.x; t < INF_ * HH; t += 256) { sW[t] = W1f[t]; sL[t] = Wl1f[t]; }
        if (threadIdx.x < HH) sb[threadIdx.x] = ((const float*)bl1p)[threadIdx.x];
    } else {
        const unsigned short* W1u  = (const unsigned short*)W1p;
        const unsigned short* Wl1u = (const unsigned short*)Wl1p;
        for (int t = threadIdx.x; t < INF_ * HH; t += 256) { sW[t] = bfu2f(W1u[t]); sL[t] = bfu2f(Wl1u[t]); }
        if (threadIdx.x < HH) sb[threadIdx.x] = bfu2f(((const unsigned short*)bl1p)[threadIdx.x]);
    }
    __syncthreads();

    int i = blockIdx.x * 256 + threadIdx.x;
    if (i >= NN) return;

    float a[HH], l[HH];
#pragma unroll
    for (int f = 0; f < HH; f++) { a[f] = 0.f; l[f] = 0.f; }

    for (int k0 = 0; k0 < INF_ / 8; k0++) {
        float xv[8];
        if (flag) {
            const float4* xr = (const float4*)((const float*)xp + (size_t)i * INF_);
            float4 r0 = xr[k0 * 2], r1 = xr[k0 * 2 + 1];
            xv[0] = r0.x; xv[1] = r0.y; xv[2] = r0.z; xv[3] = r0.w;
            xv[4] = r1.x; xv[5] = r1.y; xv[6] = r1.z; xv[7] = r1.w;
        } else {
            const uint4* xr = (const uint4*)((const unsigned short*)xp + (size_t)i * INF_);
            uint4 v = xr[k0];
            unsigned uu[4] = { v.x, v.y, v.z, v.w };
#pragma unroll
            for (int q = 0; q < 4; q++) {
                xv[q * 2]     = __uint_as_float(uu[q] << 16);
                xv[q * 2 + 1] = __uint_as_float(uu[q] & 0xffff0000u);
            }
        }
#pragma unroll
        for (int j = 0; j < 8; j++) {
            float xj = xv[j];
            int k = k0 * 8 + j;
#pragma unroll
            for (int f = 0; f < HH; f++) {
                a[f] = fmaf(xj, sW[k * HH + f], a[f]);
                l[f] = fmaf(xj, sL[k * HH + f], l[f]);
            }
        }
    }
    float di = dinv[i];
#pragma unroll
    for (int f = 0; f < HH; f++) {
        A[i * HH + f] = a[f] * di;
        B[i * HH + f] = l[f] + sb[f];
    }
}

// ---- edge scatter: C[dst,:] += A[src,:]  (A pre-scaled by dinv[src]) ----
__global__ __launch_bounds__(256) void scatter_kernel(
    const int* __restrict__ src, const int* __restrict__ dst,
    const float* __restrict__ A, float* __restrict__ C)
{
    int t = blockIdx.x * 256 + threadIdx.x;   // E*16 = 12.8M
    if (t >= EE * HH) return;
    int e = t >> 4, f = t & 15;
    int s = src[e], d = dst[e];
    atomicAdd(&C[d * HH + f], A[s * HH + f]);
}

// ---- combine layer1: D = relu(dinv*(C+A) + b) + B ----
__global__ __launch_bounds__(256) void combine_kernel(
    const float* __restrict__ dinv, const float* __restrict__ A,
    const float* __restrict__ B, const float* __restrict__ C,
    const void* __restrict__ bias, const int* __restrict__ flagp, float* __restrict__ D)
{
    int t = blockIdx.x * 256 + threadIdx.x;
    if (t >= NN * HH) return;
    int i = t >> 4, f = t & 15;
    float bf = flagp[0] ? ((const float*)bias)[f] : bfu2f(((const unsigned short*)bias)[f]);
    float conv = dinv[i] * (C[t] + A[t]) + bf;
    D[t] = fmaxf(conv, 0.f) + B[t];
}

// ---- combine layer2 emitting hs3 = out2 * dinv into A (in place) ----
__global__ __launch_bounds__(256) void combine2_kernel(
    const float* __restrict__ dinv, float* __restrict__ A,
    const float* __restrict__ B, const float* __restrict__ C,
    const void* __restrict__ bias, const int* __restrict__ flagp)
{
    int t = blockIdx.x * 256 + threadIdx.x;
    if (t >= NN * HH) return;
    int i = t >> 4, f = t & 15;
    float bf = flagp[0] ? ((const float*)bias)[f] : bfu2f(((const unsigned short*)bias)[f]);
    float di = dinv[i];
    float conv = di * (C[t] + A[t]) + bf;
    float o = fmaxf(conv, 0.f) + B[t];
    A[t] = o * di;
}

// ---- layer2 linear: A = (D@W2)*dinv, B = D@Wl2 + bl2 ----
__global__ __launch_bounds__(256) void lin2_kernel(
    const float* __restrict__ D, const void* __restrict__ W2p,
    const void* __restrict__ Wl2p, const void* __restrict__ bl2p,
    const float* __restrict__ dinv, const int* __restrict__ flagp,
    float* __restrict__ A, float* __restrict__ B)
{
    __shared__ float sW[HH * HH];
    __shared__ float sL[HH * HH];
    __shared__ float sb[HH];
    const int flag = flagp[0];
    if (flag) {
        for (int t = threadIdx.x; t < HH * HH; t += 256) {
            sW[t] = ((const float*)W2p)[t];
            sL[t] = ((const float*)Wl2p)[t];
        }
        if (threadIdx.x < HH) sb[threadIdx.x] = ((const float*)bl2p)[threadIdx.x];
    } else {
        for (int t = threadIdx.x; t < HH * HH; t += 256) {
            sW[t] = bfu2f(((const unsigned short*)W2p)[t]);
            sL[t] = bfu2f(((const unsigned short*)Wl2p)[t]);
        }
        if (threadIdx.x < HH) sb[threadIdx.x] = bfu2f(((const unsigned short*)bl2p)[threadIdx.x]);
    }
    __syncthreads();

    int i = blockIdx.x * 256 + threadIdx.x;
    if (i >= NN) return;

    float z[HH];
    const float4* dr = (const float4*)(D + (size_t)i * HH);
#pragma unroll
    for (int q = 0; q < 4; q++) {
        float4 r = dr[q];
        z[q * 4 + 0] = r.x; z[q * 4 + 1] = r.y; z[q * 4 + 2] = r.z; z[q * 4 + 3] = r.w;
    }
    float a[HH], l[HH];
#pragma unroll
    for (int f = 0; f < HH; f++) { a[f] = 0.f; l[f] = 0.f; }
#pragma unroll
    for (int k = 0; k < HH; k++) {
        float zk = z[k];
#pragma unroll
        for (int f = 0; f < HH; f++) {
            a[f] = fmaf(zk, sW[k * HH + f], a[f]);
            l[f] = fmaf(zk, sL[k * HH + f], l[f]);
        }
    }
    float di = dinv[i];
#pragma unroll
    for (int f = 0; f < HH; f++) {
        A[i * HH + f] = a[f] * di;
        B[i * HH + f] = l[f] + sb[f];
    }
}

// ---- final: z = dinv*(C+A); y = z@Wo + bo; log_softmax; dual-dtype out ----
__global__ __launch_bounds__(256) void final_kernel(
    const float* __restrict__ dinv, const float* __restrict__ A,
    const float* __restrict__ C, const void* __restrict__ Wop,
    const void* __restrict__ bop, const int* __restrict__ flagp, void* __restrict__ outp)
{
    __shared__ float sW[HH * OUTC];   // 19.2 KB
    __shared__ float sb[OUTC];
    const int flag = flagp[0];
    if (flag) {
        for (int t = threadIdx.x; t < HH * OUTC; t += 256) sW[t] = ((const float*)Wop)[t];
        for (int t = threadIdx.x; t < OUTC; t += 256)      sb[t] = ((const float*)bop)[t];
    } else {
        for (int t = threadIdx.x; t < HH * OUTC; t += 256) sW[t] = bfu2f(((const unsigned short*)Wop)[t]);
        for (int t = threadIdx.x; t < OUTC; t += 256)      sb[t] = bfu2f(((const unsigned short*)bop)[t]);
    }
    __syncthreads();

    int wave = threadIdx.x >> 6, lane = threadIdx.x & 63;
    int gw = blockIdx.x * 4 + wave;
    int nw = gridDim.x * 4;

    for (int i = gw; i < NN; i += nw) {
        float di = dinv[i];
        float z[HH];
#pragma unroll
        for (int f = 0; f < HH; f++)
            z[f] = di * (C[i * HH + f] + A[i * HH + f]);

        float y[5];
        float m = -1e30f;
#pragma unroll
        for (int jj = 0; jj < 5; jj++) {
            int j = lane + jj * 64;
            float acc = 0.f;
            if (j < OUTC) {
                acc = sb[j];
#pragma unroll
                for (int f = 0; f < HH; f++) acc = fmaf(z[f], sW[f * OUTC + j], acc);
                m = fmaxf(m, acc);
            }
            y[jj] = acc;
        }
#pragma unroll
        for (int o = 32; o > 0; o >>= 1) m = fmaxf(m, __shfl_xor(m, o));
        float s = 0.f;
#pragma unroll
        for (int jj = 0; jj < 5; jj++) {
            int j = lane + jj * 64;
            if (j < OUTC) s += __expf(y[jj] - m);
        }
#pragma unroll
        for (int o = 32; o > 0; o >>= 1) s += __shfl_xor(s, o);
        float lse = m + __logf(s);
#pragma unroll
        for (int jj = 0; jj < 5; jj++) {
            int j = lane + jj * 64;
            if (j < OUTC) {
                float v = y[jj] - lse;
                size_t ofs = (size_t)i * OUTC + j;
                if (flag) ((float*)outp)[ofs] = v;
                else      ((__hip_bfloat16*)outp)[ofs] = __float2bfloat16(v);
            }
        }
    }
}

extern "C" void kernel_launch(void* const* d_in, const int* in_sizes, int n_in,
                              void* d_out, int out_size, void* d_ws, size_t ws_size,
                              hipStream_t stream) {
    const void* x   = d_in[0];
    const int*  ei  = (const int*)d_in[1];
    const void* W1  = d_in[2];
    const void* b1  = d_in[3];
    const void* Wl1 = d_in[4];
    const void* bl1 = d_in[5];
    const void* W2  = d_in[6];
    const void* b2  = d_in[7];
    const void* Wl2 = d_in[8];
    const void* bl2 = d_in[9];
    const void* Wo  = d_in[10];
    const void* bo  = d_in[11];

    const int* srcp = ei;        // edge_index[0]
    const int* dstp = ei + EE;   // edge_index[1]

    float* ws   = (float*)d_ws;
    int*   flag = (int*)ws;               // [0..3] (16B slot)
    float* dinv = ws + 4;                 // NN
    float* A    = ws + 50008;             // NN*HH   (16B-aligned)
    float* B    = A + NN * HH;
    float* C    = B + NN * HH;
    float* D    = C + NN * HH;

    const int gE  = (EE + 255) / 256;
    const int gN  = (NN + 255) / 256;
    const int gNH = (NN * HH + 255) / 256;
    const int gS  = (EE * HH + 255) / 256;

    // dtype detect
    detect_kernel<<<1, 64, 0, stream>>>((const unsigned*)x, flag);

    // degree / dinv
    hipMemsetAsync(dinv, 0, NN * sizeof(float), stream);
    deg_kernel<<<gE, 256, 0, stream>>>(dstp, dinv);
    dinv_kernel<<<gN, 256, 0, stream>>>(dinv);

    // layer 1
    lin1_kernel<<<gN, 256, 0, stream>>>(x, W1, Wl1, bl1, dinv, flag, A, B);
    hipMemsetAsync(C, 0, NN * HH * sizeof(float), stream);
    scatter_kernel<<<gS, 256, 0, stream>>>(srcp, dstp, A, C);
    combine_kernel<<<gNH, 256, 0, stream>>>(dinv, A, B, C, b1, flag, D);

    // layer 2
    lin2_kernel<<<gN, 256, 0, stream>>>(D, W2, Wl2, bl2, dinv, flag, A, B);
    hipMemsetAsync(C, 0, NN * HH * sizeof(float), stream);
    scatter_kernel<<<gS, 256, 0, stream>>>(srcp, dstp, A, C);
    combine2_kernel<<<gNH, 256, 0, stream>>>(dinv, A, B, C, b2, flag);   // A <- out2*dinv

    // output layer aggregation (pre-Wo, H=16 wide)
    hipMemsetAsync(C, 0, NN * HH * sizeof(float), stream);
    scatter_kernel<<<gS, 256, 0, stream>>>(srcp, dstp, A, C);

    // final matmul + log_softmax
    final_kernel<<<1250, 256, 0, stream>>>(dinv, A, C, Wo, bo, flag, d_out);
}

// Round 3
// 448.086 us; speedup vs baseline: 1.0612x; 1.0612x over previous
//
#include <hip/hip_runtime.h>
#include <hip/hip_bf16.h>

#define NN   50000
#define EE   800000
#define INF_ 128
#define HH   16
#define OUTC 300

__device__ __forceinline__ float bfu2f(unsigned short u) {
    return __uint_as_float(((unsigned)u) << 16);
}

// ---- dtype detect: scan low-half-bf16 of first 256 words of x ----
__global__ __launch_bounds__(64) void detect_kernel(const unsigned* __restrict__ xw, int* __restrict__ flag) {
    int t = threadIdx.x;
    int hits = 0;
#pragma unroll
    for (int q = 0; q < 4; q++) {
        unsigned w = xw[t * 4 + q];
        float lo = __uint_as_float(w << 16);
        if (!(fabsf(lo) < 1e4f)) hits++;
    }
#pragma unroll
    for (int o = 32; o > 0; o >>= 1) hits += __shfl_xor(hits, o);
    if (t == 0) flag[0] = (hits > 8) ? 1 : 0;   // 1 => inputs are fp32
}

// ---- histogram of dst ----
__global__ __launch_bounds__(256) void count_kernel(const int* __restrict__ dst, int* __restrict__ cnt) {
    int e = blockIdx.x * 256 + threadIdx.x;
    if (e < EE) atomicAdd(&cnt[dst[e]], 1);
}

// ---- exclusive scan of cnt -> off, fused dinv = rsqrt(cnt+1). 1 block, 1024 thr ----
#define SCAN_T 1024
#define CHUNK  ((NN + SCAN_T - 1) / SCAN_T)
__global__ __launch_bounds__(SCAN_T) void scan_dinv_kernel(
    const int* __restrict__ cnt, int* __restrict__ off, float* __restrict__ dinv)
{
    __shared__ int sdata[SCAN_T];
    int t = threadIdx.x;
    int lo = t * CHUNK, hi = min(lo + CHUNK, NN);
    int s = 0;
    for (int i = lo; i < hi; i++) s += cnt[i];
    sdata[t] = s;
    __syncthreads();
    // Hillis-Steele inclusive scan
    for (int d = 1; d < SCAN_T; d <<= 1) {
        int v = (t >= d) ? sdata[t - d] : 0;
        __syncthreads();
        sdata[t] += v;
        __syncthreads();
    }
    int base = sdata[t] - s;   // exclusive prefix of this chunk
    for (int i = lo; i < hi; i++) {
        off[i] = base;
        int c = cnt[i];
        base += c;
        dinv[i] = rsqrtf((float)c + 1.0f);
    }
    if (t == 0) off[NN] = EE;
}

// ---- placement: csr_src[off[d] + cur[d]++] = src[e] ----
__global__ __launch_bounds__(256) void place_kernel(
    const int* __restrict__ src, const int* __restrict__ dst,
    const int* __restrict__ off, int* __restrict__ cur, int* __restrict__ csr_src)
{
    int e = blockIdx.x * 256 + threadIdx.x;
    if (e >= EE) return;
    int d = dst[e];
    int p = off[d] + atomicAdd(&cur[d], 1);
    csr_src[p] = src[e];
}

// ---- layer1 linear: A = (x@W1)*dinv, B = x@Wl1 + bl1 ----
__global__ __launch_bounds__(256) void lin1_kernel(
    const void* __restrict__ xp, const void* __restrict__ W1p,
    const void* __restrict__ Wl1p, const void* __restrict__ bl1p,
    const float* __restrict__ dinv, const int* __restrict__ flagp,
    float* __restrict__ A, float* __restrict__ B)
{
    __shared__ float sW[INF_ * HH];
    __shared__ float sL[INF_ * HH];
    __shared__ float sb[HH];
    const int flag = flagp[0];
    if (flag) {
        for (int t = threadIdx.x; t < INF_ * HH; t += 256) {
            sW[t] = ((const float*)W1p)[t];
            sL[t] = ((const float*)Wl1p)[t];
        }
        if (threadIdx.x < HH) sb[threadIdx.x] = ((const float*)bl1p)[threadIdx.x];
    } else {
        for (int t = threadIdx.x; t < INF_ * HH; t += 256) {
            sW[t] = bfu2f(((const unsigned short*)W1p)[t]);
            sL[t] = bfu2f(((const unsigned short*)Wl1p)[t]);
        }
        if (threadIdx.x < HH) sb[threadIdx.x] = bfu2f(((const unsigned short*)bl1p)[threadIdx.x]);
    }
    __syncthreads();

    int i = blockIdx.x * 256 + threadIdx.x;
    if (i >= NN) return;

    float a[HH], l[HH];
#pragma unroll
    for (int f = 0; f < HH; f++) { a[f] = 0.f; l[f] = 0.f; }

    for (int k0 = 0; k0 < INF_ / 8; k0++) {
        float xv[8];
        if (flag) {
            const float4* xr = (const float4*)((const float*)xp + (size_t)i * INF_);
            float4 r0 = xr[k0 * 2], r1 = xr[k0 * 2 + 1];
            xv[0] = r0.x; xv[1] = r0.y; xv[2] = r0.z; xv[3] = r0.w;
            xv[4] = r1.x; xv[5] = r1.y; xv[6] = r1.z; xv[7] = r1.w;
        } else {
            const uint4* xr = (const uint4*)((const unsigned short*)xp + (size_t)i * INF_);
            uint4 v = xr[k0];
            unsigned uu[4] = { v.x, v.y, v.z, v.w };
#pragma unroll
            for (int q = 0; q < 4; q++) {
                xv[q * 2]     = __uint_as_float(uu[q] << 16);
                xv[q * 2 + 1] = __uint_as_float(uu[q] & 0xffff0000u);
            }
        }
#pragma unroll
        for (int j = 0; j < 8; j++) {
            float xj = xv[j];
            int k = k0 * 8 + j;
#pragma unroll
            for (int f = 0; f < HH; f++) {
                a[f] = fmaf(xj, sW[k * HH + f], a[f]);
                l[f] = fmaf(xj, sL[k * HH + f], l[f]);
            }
        }
    }
    float di = dinv[i];
#pragma unroll
    for (int f = 0; f < HH; f++) {
        A[i * HH + f] = a[f] * di;
        B[i * HH + f] = l[f] + sb[f];
    }
}

// ---- fused gather + combine. One wave per node; 4 edges x 16 feats per step.
// mode 0: B[i] = relu(dinv*(agg + A[i]) + b) + B[i]          (hidden layer)
// mode 1: B[i] = (relu(dinv*(agg + A[i]) + b) + B[i]) * dinv (pre-scaled for next gather)
__global__ __launch_bounds__(256) void gather_combine_kernel(
    const int* __restrict__ off, const int* __restrict__ csr,
    const float* __restrict__ dinv, const float* __restrict__ A,
    float* __restrict__ B, const void* __restrict__ bias,
    const int* __restrict__ flagp, int mode)
{
    int wid = (blockIdx.x * 256 + threadIdx.x) >> 6;   // node id
    int lane = threadIdx.x & 63;
    if (wid >= NN) return;
    int f = lane & 15, sub = lane >> 4;
    int s0 = off[wid], s1 = off[wid + 1];
    float acc = 0.f;
    for (int p = s0 + sub; p < s1; p += 4) {
        int s = csr[p];                  // broadcast within sub-group
        acc += A[s * HH + f];            // 64B row, 4 rows/instr across subs
    }
    acc += __shfl_xor(acc, 16);
    acc += __shfl_xor(acc, 32);
    if (sub == 0) {
        float bf = flagp[0] ? ((const float*)bias)[f] : bfu2f(((const unsigned short*)bias)[f]);
        float di = dinv[wid];
        float conv = di * (acc + A[wid * HH + f]) + bf;
        float o = fmaxf(conv, 0.f) + B[wid * HH + f];
        B[wid * HH + f] = mode ? o * di : o;
    }
}

// ---- layer2 linear: reads h1 from B; A = (h1@W2)*dinv, B = h1@Wl2 + bl2 ----
__global__ __launch_bounds__(256) void lin2_kernel(
    float* __restrict__ B, const void* __restrict__ W2p,
    const void* __restrict__ Wl2p, const void* __restrict__ bl2p,
    const float* __restrict__ dinv, const int* __restrict__ flagp,
    float* __restrict__ A)
{
    __shared__ float sW[HH * HH];
    __shared__ float sL[HH * HH];
    __shared__ float sb[HH];
    const int flag = flagp[0];
    if (flag) {
        for (int t = threadIdx.x; t < HH * HH; t += 256) {
            sW[t] = ((const float*)W2p)[t];
            sL[t] = ((const float*)Wl2p)[t];
        }
        if (threadIdx.x < HH) sb[threadIdx.x] = ((const float*)bl2p)[threadIdx.x];
    } else {
        for (int t = threadIdx.x; t < HH * HH; t += 256) {
            sW[t] = bfu2f(((const unsigned short*)W2p)[t]);
            sL[t] = bfu2f(((const unsigned short*)Wl2p)[t]);
        }
        if (threadIdx.x < HH) sb[threadIdx.x] = bfu2f(((const unsigned short*)bl2p)[threadIdx.x]);
    }
    __syncthreads();

    int i = blockIdx.x * 256 + threadIdx.x;
    if (i >= NN) return;

    float z[HH];
    const float4* dr = (const float4*)(B + (size_t)i * HH);
#pragma unroll
    for (int q = 0; q < 4; q++) {
        float4 r = dr[q];
        z[q * 4 + 0] = r.x; z[q * 4 + 1] = r.y; z[q * 4 + 2] = r.z; z[q * 4 + 3] = r.w;
    }
    float a[HH], l[HH];
#pragma unroll
    for (int f = 0; f < HH; f++) { a[f] = 0.f; l[f] = 0.f; }
#pragma unroll
    for (int k = 0; k < HH; k++) {
        float zk = z[k];
#pragma unroll
        for (int f = 0; f < HH; f++) {
            a[f] = fmaf(zk, sW[k * HH + f], a[f]);
            l[f] = fmaf(zk, sL[k * HH + f], l[f]);
        }
    }
    float di = dinv[i];
#pragma unroll
    for (int f = 0; f < HH; f++) {
        A[i * HH + f] = a[f] * di;
        B[i * HH + f] = l[f] + sb[f];
    }
}

// ---- final: gather Z (=out2*dinv, in B) via CSR, z = dinv*(agg+Z[i]),
//      y = z@Wo + bo, log_softmax, dual-dtype out ----
__global__ __launch_bounds__(256) void final_kernel(
    const int* __restrict__ off, const int* __restrict__ csr,
    const float* __restrict__ dinv, const float* __restrict__ Z,
    const void* __restrict__ Wop, const void* __restrict__ bop,
    const int* __restrict__ flagp, void* __restrict__ outp)
{
    __shared__ float sW[HH * OUTC];   // 19.2 KB
    __shared__ float sb[OUTC];
    const int flag = flagp[0];
    if (flag) {
        for (int t = threadIdx.x; t < HH * OUTC; t += 256) sW[t] = ((const float*)Wop)[t];
        for (int t = threadIdx.x; t < OUTC; t += 256)      sb[t] = ((const float*)bop)[t];
    } else {
        for (int t = threadIdx.x; t < HH * OUTC; t += 256) sW[t] = bfu2f(((const unsigned short*)Wop)[t]);
        for (int t = threadIdx.x; t < OUTC; t += 256)      sb[t] = bfu2f(((const unsigned short*)bop)[t]);
    }
    __syncthreads();

    int wave = threadIdx.x >> 6, lane = threadIdx.x & 63;
    int f = lane & 15, sub = lane >> 4;
    int gw = blockIdx.x * 4 + wave;
    int nw = gridDim.x * 4;

    for (int i = gw; i < NN; i += nw) {
        int s0 = off[i], s1 = off[i + 1];
        float acc = 0.f;
        for (int p = s0 + sub; p < s1; p += 4) {
            int s = csr[p];
            acc += Z[s * HH + f];
        }
        acc += __shfl_xor(acc, 16);
        acc += __shfl_xor(acc, 32);
        float zf = dinv[i] * (acc + Z[i * HH + f]);   // feature f of z, all lanes
        float z[HH];
#pragma unroll
        for (int k = 0; k < HH; k++) z[k] = __shfl(zf, k);  // lanes 0..15 hold feats 0..15

        float y[5];
        float m = -1e30f;
#pragma unroll
        for (int jj = 0; jj < 5; jj++) {
            int j = lane + jj * 64;
            float a2 = 0.f;
            if (j < OUTC) {
                a2 = sb[j];
#pragma unroll
                for (int k = 0; k < HH; k++) a2 = fmaf(z[k], sW[k * OUTC + j], a2);
                m = fmaxf(m, a2);
            }
            y[jj] = a2;
        }
#pragma unroll
        for (int o = 32; o > 0; o >>= 1) m = fmaxf(m, __shfl_xor(m, o));
        float s = 0.f;
#pragma unroll
        for (int jj = 0; jj < 5; jj++) {
            int j = lane + jj * 64;
            if (j < OUTC) s += __expf(y[jj] - m);
        }
#pragma unroll
        for (int o = 32; o > 0; o >>= 1) s += __shfl_xor(s, o);
        float lse = m + __logf(s);
#pragma unroll
        for (int jj = 0; jj < 5; jj++) {
            int j = lane + jj * 64;
            if (j < OUTC) {
                float v = y[jj] - lse;
                size_t ofs = (size_t)i * OUTC + j;
                if (flag) ((float*)outp)[ofs] = v;
                else      ((__hip_bfloat16*)outp)[ofs] = __float2bfloat16(v);
            }
        }
    }
}

extern "C" void kernel_launch(void* const* d_in, const int* in_sizes, int n_in,
                              void* d_out, int out_size, void* d_ws, size_t ws_size,
                              hipStream_t stream) {
    const void* x   = d_in[0];
    const int*  ei  = (const int*)d_in[1];
    const void* W1  = d_in[2];
    const void* b1  = d_in[3];
    const void* Wl1 = d_in[4];
    const void* bl1 = d_in[5];
    const void* W2  = d_in[6];
    const void* b2  = d_in[7];
    const void* Wl2 = d_in[8];
    const void* bl2 = d_in[9];
    const void* Wo  = d_in[10];
    const void* bo  = d_in[11];

    const int* srcp = ei;        // edge_index[0]
    const int* dstp = ei + EE;   // edge_index[1]

    // ws layout (4-byte words), all regions 16B-aligned:
    //   flag[4] | cnt[NN] | off[NN+1 ->pad] | csr_src[EE] | dinv[NN] | A[NN*16] | B[NN*16]
    char* wsb = (char*)d_ws;
    int*   flag    = (int*)wsb;                       // word 0
    int*   cnt     = (int*)(wsb + 4 * 4);             // word 4
    int*   off     = (int*)(wsb + 4 * 50004);         // word 50004 .. 100005
    int*   csr_src = (int*)(wsb + 4 * 100008);        // word 100008 .. 900008
    float* dinv    = (float*)(wsb + 4 * 900008);      // word 900008 .. 950008
    float* A       = (float*)(wsb + 4 * 950008);      // .. 1750008
    float* B       = (float*)(wsb + 4 * 1750008);     // .. 2550008  (10.2 MB)

    const int gE = (EE + 255) / 256;
    const int gN = (NN + 255) / 256;
    const int gG = (NN * 64 + 255) / 256;   // wave-per-node gathers

    // dtype detect
    detect_kernel<<<1, 64, 0, stream>>>((const unsigned*)x, flag);

    // CSR build + dinv
    hipMemsetAsync(cnt, 0, NN * sizeof(int), stream);
    count_kernel<<<gE, 256, 0, stream>>>(dstp, cnt);
    scan_dinv_kernel<<<1, SCAN_T, 0, stream>>>(cnt, off, dinv);
    hipMemsetAsync(cnt, 0, NN * sizeof(int), stream);   // reuse cnt as cursor
    place_kernel<<<gE, 256, 0, stream>>>(srcp, dstp, off, cnt, csr_src);

    // layer 1: lin -> gather+combine (B <- h1)
    lin1_kernel<<<gN, 256, 0, stream>>>(x, W1, Wl1, bl1, dinv, flag, A, B);
    gather_combine_kernel<<<gG, 256, 0, stream>>>(off, csr_src, dinv, A, B, b1, flag, 0);

    // layer 2: lin -> gather+combine (B <- out2*dinv)
    lin2_kernel<<<gN, 256, 0, stream>>>(B, W2, Wl2, bl2, dinv, flag, A);
    gather_combine_kernel<<<gG, 256, 0, stream>>>(off, csr_src, dinv, A, B, b2, flag, 1);

    // output layer: gather + Wo matmul + log_softmax fused
    final_kernel<<<1250, 256, 0, stream>>>(off, csr_src, dinv, B, Wo, bo, flag, d_out);
}

// Round 4
// 360.951 us; speedup vs baseline: 1.3174x; 1.2414x over previous
//
#include <hip/hip_runtime.h>
#include <hip/hip_bf16.h>

#define NN   50000
#define EE   800000
#define INF_ 128
#define HH   16
#define OUTC 300
#define SB   196   // scan blocks: 196*256 = 50176 >= NN

__device__ __forceinline__ float bfu2f(unsigned short u) {
    return __uint_as_float(((unsigned)u) << 16);
}

// ---- dtype detect: scan low-half-bf16 of first 256 words of x ----
__global__ __launch_bounds__(64) void detect_kernel(const unsigned* __restrict__ xw, int* __restrict__ flag) {
    int t = threadIdx.x;
    int hits = 0;
#pragma unroll
    for (int q = 0; q < 4; q++) {
        unsigned w = xw[t * 4 + q];
        float lo = __uint_as_float(w << 16);
        if (!(fabsf(lo) < 1e4f)) hits++;
    }
#pragma unroll
    for (int o = 32; o > 0; o >>= 1) hits += __shfl_xor(hits, o);
    if (t == 0) flag[0] = (hits > 8) ? 1 : 0;   // 1 => inputs are fp32
}

// ---- histogram of dst ----
__global__ __launch_bounds__(256) void count_kernel(const int* __restrict__ dst, int* __restrict__ cnt) {
    int e = blockIdx.x * 256 + threadIdx.x;
    if (e < EE) atomicAdd(&cnt[dst[e]], 1);
}

// ---- hierarchical scan stage 1: block-local exclusive scan + block sums ----
__global__ __launch_bounds__(256) void scan1_kernel(
    const int* __restrict__ cnt, int* __restrict__ off, int* __restrict__ bsum)
{
    __shared__ int sd[256];
    int t = threadIdx.x;
    int i = blockIdx.x * 256 + t;
    int v = (i < NN) ? cnt[i] : 0;
    sd[t] = v;
    __syncthreads();
    for (int d = 1; d < 256; d <<= 1) {
        int u = (t >= d) ? sd[t - d] : 0;
        __syncthreads();
        sd[t] += u;
        __syncthreads();
    }
    if (i < NN) off[i] = sd[t] - v;          // exclusive within block
    if (t == 255) bsum[blockIdx.x] = sd[255]; // block total
}

// ---- stage 2: scan the 196 block sums (1 block) ----
__global__ __launch_bounds__(256) void scan2_kernel(const int* __restrict__ bsum, int* __restrict__ boff) {
    __shared__ int sd[256];
    int t = threadIdx.x;
    int v = (t < SB) ? bsum[t] : 0;
    sd[t] = v;
    __syncthreads();
    for (int d = 1; d < 256; d <<= 1) {
        int u = (t >= d) ? sd[t - d] : 0;
        __syncthreads();
        sd[t] += u;
        __syncthreads();
    }
    if (t < SB) boff[t] = sd[t] - v;          // exclusive block offset
}

// ---- stage 3: add block offsets, fused dinv = rsqrt(cnt+1), off[NN]=EE ----
__global__ __launch_bounds__(256) void scan3_kernel(
    const int* __restrict__ cnt, int* __restrict__ off,
    const int* __restrict__ boff, float* __restrict__ dinv)
{
    int i = blockIdx.x * 256 + threadIdx.x;
    if (i < NN) {
        off[i] += boff[blockIdx.x];
        dinv[i] = rsqrtf((float)cnt[i] + 1.0f);
    }
    if (i == NN) off[NN] = EE;
}

// ---- placement: csr_src[off[d] + cur[d]++] = src[e] ----
__global__ __launch_bounds__(256) void place_kernel(
    const int* __restrict__ src, const int* __restrict__ dst,
    const int* __restrict__ off, int* __restrict__ cur, int* __restrict__ csr_src)
{
    int e = blockIdx.x * 256 + threadIdx.x;
    if (e >= EE) return;
    int d = dst[e];
    int p = off[d] + atomicAdd(&cur[d], 1);
    csr_src[p] = src[e];
}

// ---- layer1 linear: A = (x@W1)*dinv, B = x@Wl1 + bl1 ----
__global__ __launch_bounds__(256) void lin1_kernel(
    const void* __restrict__ xp, const void* __restrict__ W1p,
    const void* __restrict__ Wl1p, const void* __restrict__ bl1p,
    const float* __restrict__ dinv, const int* __restrict__ flagp,
    float* __restrict__ A, float* __restrict__ B)
{
    __shared__ float sW[INF_ * HH];
    __shared__ float sL[INF_ * HH];
    __shared__ float sb[HH];
    const int flag = flagp[0];
    if (flag) {
        for (int t = threadIdx.x; t < INF_ * HH; t += 256) {
            sW[t] = ((const float*)W1p)[t];
            sL[t] = ((const float*)Wl1p)[t];
        }
        if (threadIdx.x < HH) sb[threadIdx.x] = ((const float*)bl1p)[threadIdx.x];
    } else {
        for (int t = threadIdx.x; t < INF_ * HH; t += 256) {
            sW[t] = bfu2f(((const unsigned short*)W1p)[t]);
            sL[t] = bfu2f(((const unsigned short*)Wl1p)[t]);
        }
        if (threadIdx.x < HH) sb[threadIdx.x] = bfu2f(((const unsigned short*)bl1p)[threadIdx.x]);
    }
    __syncthreads();

    int i = blockIdx.x * 256 + threadIdx.x;
    if (i >= NN) return;

    float a[HH], l[HH];
#pragma unroll
    for (int f = 0; f < HH; f++) { a[f] = 0.f; l[f] = 0.f; }

    for (int k0 = 0; k0 < INF_ / 8; k0++) {
        float xv[8];
        if (flag) {
            const float4* xr = (const float4*)((const float*)xp + (size_t)i * INF_);
            float4 r0 = xr[k0 * 2], r1 = xr[k0 * 2 + 1];
            xv[0] = r0.x; xv[1] = r0.y; xv[2] = r0.z; xv[3] = r0.w;
            xv[4] = r1.x; xv[5] = r1.y; xv[6] = r1.z; xv[7] = r1.w;
        } else {
            const uint4* xr = (const uint4*)((const unsigned short*)xp + (size_t)i * INF_);
            uint4 v = xr[k0];
            unsigned uu[4] = { v.x, v.y, v.z, v.w };
#pragma unroll
            for (int q = 0; q < 4; q++) {
                xv[q * 2]     = __uint_as_float(uu[q] << 16);
                xv[q * 2 + 1] = __uint_as_float(uu[q] & 0xffff0000u);
            }
        }
#pragma unroll
        for (int j = 0; j < 8; j++) {
            float xj = xv[j];
            int k = k0 * 8 + j;
#pragma unroll
            for (int f = 0; f < HH; f++) {
                a[f] = fmaf(xj, sW[k * HH + f], a[f]);
                l[f] = fmaf(xj, sL[k * HH + f], l[f]);
            }
        }
    }
    float di = dinv[i];
#pragma unroll
    for (int f = 0; f < HH; f++) {
        A[i * HH + f] = a[f] * di;
        B[i * HH + f] = l[f] + sb[f];
    }
}

// ---- fused gather + combine. One wave per node; 4 edges x 16 feats per step.
// mode 0: B[i] = relu(dinv*(agg + A[i]) + b) + B[i]
// mode 1: B[i] = (relu(dinv*(agg + A[i]) + b) + B[i]) * dinv
__global__ __launch_bounds__(256) void gather_combine_kernel(
    const int* __restrict__ off, const int* __restrict__ csr,
    const float* __restrict__ dinv, const float* __restrict__ A,
    float* __restrict__ B, const void* __restrict__ bias,
    const int* __restrict__ flagp, int mode)
{
    int wid = (blockIdx.x * 256 + threadIdx.x) >> 6;   // node id
    int lane = threadIdx.x & 63;
    if (wid >= NN) return;
    int f = lane & 15, sub = lane >> 4;
    int s0 = off[wid], s1 = off[wid + 1];
    float acc = 0.f;
    for (int p = s0 + sub; p < s1; p += 4) {
        int s = csr[p];
        acc += A[s * HH + f];
    }
    acc += __shfl_xor(acc, 16);
    acc += __shfl_xor(acc, 32);
    if (sub == 0) {
        float bf = flagp[0] ? ((const float*)bias)[f] : bfu2f(((const unsigned short*)bias)[f]);
        float di = dinv[wid];
        float conv = di * (acc + A[wid * HH + f]) + bf;
        float o = fmaxf(conv, 0.f) + B[wid * HH + f];
        B[wid * HH + f] = mode ? o * di : o;
    }
}

// ---- layer2 linear: reads h1 from B; A = (h1@W2)*dinv, B = h1@Wl2 + bl2 ----
__global__ __launch_bounds__(256) void lin2_kernel(
    float* __restrict__ B, const void* __restrict__ W2p,
    const void* __restrict__ Wl2p, const void* __restrict__ bl2p,
    const float* __restrict__ dinv, const int* __restrict__ flagp,
    float* __restrict__ A)
{
    __shared__ float sW[HH * HH];
    __shared__ float sL[HH * HH];
    __shared__ float sb[HH];
    const int flag = flagp[0];
    if (flag) {
        for (int t = threadIdx.x; t < HH * HH; t += 256) {
            sW[t] = ((const float*)W2p)[t];
            sL[t] = ((const float*)Wl2p)[t];
        }
        if (threadIdx.x < HH) sb[threadIdx.x] = ((const float*)bl2p)[threadIdx.x];
    } else {
        for (int t = threadIdx.x; t < HH * HH; t += 256) {
            sW[t] = bfu2f(((const unsigned short*)W2p)[t]);
            sL[t] = bfu2f(((const unsigned short*)Wl2p)[t]);
        }
        if (threadIdx.x < HH) sb[threadIdx.x] = bfu2f(((const unsigned short*)bl2p)[threadIdx.x]);
    }
    __syncthreads();

    int i = blockIdx.x * 256 + threadIdx.x;
    if (i >= NN) return;

    float z[HH];
    const float4* dr = (const float4*)(B + (size_t)i * HH);
#pragma unroll
    for (int q = 0; q < 4; q++) {
        float4 r = dr[q];
        z[q * 4 + 0] = r.x; z[q * 4 + 1] = r.y; z[q * 4 + 2] = r.z; z[q * 4 + 3] = r.w;
    }
    float a[HH], l[HH];
#pragma unroll
    for (int f = 0; f < HH; f++) { a[f] = 0.f; l[f] = 0.f; }
#pragma unroll
    for (int k = 0; k < HH; k++) {
        float zk = z[k];
#pragma unroll
        for (int f = 0; f < HH; f++) {
            a[f] = fmaf(zk, sW[k * HH + f], a[f]);
            l[f] = fmaf(zk, sL[k * HH + f], l[f]);
        }
    }
    float di = dinv[i];
#pragma unroll
    for (int f = 0; f < HH; f++) {
        A[i * HH + f] = a[f] * di;
        B[i * HH + f] = l[f] + sb[f];
    }
}

// ---- final: gather Z (=out2*dinv, in B) via CSR, z = dinv*(agg+Z[i]),
//      y = z@Wo + bo, log_softmax, dual-dtype out ----
__global__ __launch_bounds__(256) void final_kernel(
    const int* __restrict__ off, const int* __restrict__ csr,
    const float* __restrict__ dinv, const float* __restrict__ Z,
    const void* __restrict__ Wop, const void* __restrict__ bop,
    const int* __restrict__ flagp, void* __restrict__ outp)
{
    __shared__ float sW[HH * OUTC];   // 19.2 KB
    __shared__ float sb[OUTC];
    const int flag = flagp[0];
    if (flag) {
        for (int t = threadIdx.x; t < HH * OUTC; t += 256) sW[t] = ((const float*)Wop)[t];
        for (int t = threadIdx.x; t < OUTC; t += 256)      sb[t] = ((const float*)bop)[t];
    } else {
        for (int t = threadIdx.x; t < HH * OUTC; t += 256) sW[t] = bfu2f(((const unsigned short*)Wop)[t]);
        for (int t = threadIdx.x; t < OUTC; t += 256)      sb[t] = bfu2f(((const unsigned short*)bop)[t]);
    }
    __syncthreads();

    int wave = threadIdx.x >> 6, lane = threadIdx.x & 63;
    int f = lane & 15, sub = lane >> 4;
    int gw = blockIdx.x * 4 + wave;
    int nw = gridDim.x * 4;

    for (int i = gw; i < NN; i += nw) {
        int s0 = off[i], s1 = off[i + 1];
        float acc = 0.f;
        for (int p = s0 + sub; p < s1; p += 4) {
            int s = csr[p];
            acc += Z[s * HH + f];
        }
        acc += __shfl_xor(acc, 16);
        acc += __shfl_xor(acc, 32);
        float zf = dinv[i] * (acc + Z[i * HH + f]);
        float z[HH];
#pragma unroll
        for (int k = 0; k < HH; k++) z[k] = __shfl(zf, k);

        float y[5];
        float m = -1e30f;
#pragma unroll
        for (int jj = 0; jj < 5; jj++) {
            int j = lane + jj * 64;
            float a2 = 0.f;
            if (j < OUTC) {
                a2 = sb[j];
#pragma unroll
                for (int k = 0; k < HH; k++) a2 = fmaf(z[k], sW[k * OUTC + j], a2);
                m = fmaxf(m, a2);
            }
            y[jj] = a2;
        }
#pragma unroll
        for (int o = 32; o > 0; o >>= 1) m = fmaxf(m, __shfl_xor(m, o));
        float s = 0.f;
#pragma unroll
        for (int jj = 0; jj < 5; jj++) {
            int j = lane + jj * 64;
            if (j < OUTC) s += __expf(y[jj] - m);
        }
#pragma unroll
        for (int o = 32; o > 0; o >>= 1) s += __shfl_xor(s, o);
        float lse = m + __logf(s);
#pragma unroll
        for (int jj = 0; jj < 5; jj++) {
            int j = lane + jj * 64;
            if (j < OUTC) {
                float v = y[jj] - lse;
                size_t ofs = (size_t)i * OUTC + j;
                if (flag) ((float*)outp)[ofs] = v;
                else      ((__hip_bfloat16*)outp)[ofs] = __float2bfloat16(v);
            }
        }
    }
}

extern "C" void kernel_launch(void* const* d_in, const int* in_sizes, int n_in,
                              void* d_out, int out_size, void* d_ws, size_t ws_size,
                              hipStream_t stream) {
    const void* x   = d_in[0];
    const int*  ei  = (const int*)d_in[1];
    const void* W1  = d_in[2];
    const void* b1  = d_in[3];
    const void* Wl1 = d_in[4];
    const void* bl1 = d_in[5];
    const void* W2  = d_in[6];
    const void* b2  = d_in[7];
    const void* Wl2 = d_in[8];
    const void* bl2 = d_in[9];
    const void* Wo  = d_in[10];
    const void* bo  = d_in[11];

    const int* srcp = ei;        // edge_index[0]
    const int* dstp = ei + EE;   // edge_index[1]

    // ws layout (4-byte words), 16B-aligned regions:
    char* wsb = (char*)d_ws;
    int*   flag    = (int*)wsb;                       // [0..3]
    int*   cnt     = (int*)(wsb + 4 * 4);             // 4 .. 50003
    int*   off     = (int*)(wsb + 4 * 50004);         // 50004 .. 100004
    int*   bsum    = (int*)(wsb + 4 * 100008);        // 100008 .. 100203
    int*   boff    = (int*)(wsb + 4 * 100264);        // 100264 .. 100459
    int*   csr_src = (int*)(wsb + 4 * 100520);        // 100520 .. 900519
    float* dinv    = (float*)(wsb + 4 * 900520);      // 900520 .. 950519
    float* A       = (float*)(wsb + 4 * 950520);      // .. 1750519
    float* B       = (float*)(wsb + 4 * 1750520);     // .. 2550519  (~10.2 MB)

    const int gE = (EE + 255) / 256;
    const int gN = (NN + 255) / 256;
    const int gG = (NN * 64 + 255) / 256;   // wave-per-node gathers

    // dtype detect
    detect_kernel<<<1, 64, 0, stream>>>((const unsigned*)x, flag);

    // CSR build + dinv (hierarchical scan)
    hipMemsetAsync(cnt, 0, NN * sizeof(int), stream);
    count_kernel<<<gE, 256, 0, stream>>>(dstp, cnt);
    scan1_kernel<<<SB, 256, 0, stream>>>(cnt, off, bsum);
    scan2_kernel<<<1, 256, 0, stream>>>(bsum, boff);
    scan3_kernel<<<SB, 256, 0, stream>>>(cnt, off, boff, dinv);
    hipMemsetAsync(cnt, 0, NN * sizeof(int), stream);   // reuse cnt as cursor
    place_kernel<<<gE, 256, 0, stream>>>(srcp, dstp, off, cnt, csr_src);

    // layer 1: lin -> gather+combine (B <- h1)
    lin1_kernel<<<gN, 256, 0, stream>>>(x, W1, Wl1, bl1, dinv, flag, A, B);
    gather_combine_kernel<<<gG, 256, 0, stream>>>(off, csr_src, dinv, A, B, b1, flag, 0);

    // layer 2: lin -> gather+combine (B <- out2*dinv)
    lin2_kernel<<<gN, 256, 0, stream>>>(B, W2, Wl2, bl2, dinv, flag, A);
    gather_combine_kernel<<<gG, 256, 0, stream>>>(off, csr_src, dinv, A, B, b2, flag, 1);

    // output layer: gather + Wo matmul + log_softmax fused
    final_kernel<<<1250, 256, 0, stream>>>(off, csr_src, dinv, B, Wo, bo, flag, d_out);
}

// Round 5
// 317.273 us; speedup vs baseline: 1.4987x; 1.1377x over previous
//
#include <hip/hip_runtime.h>
#include <hip/hip_bf16.h>

#define NN   50000
#define EE   800000
#define INF_ 128
#define HH   16
#define OUTC 300
#define SB   196   // scan blocks: 196*256 = 50176 >= NN

__device__ __forceinline__ float bfu2f(unsigned short u) {
    return __uint_as_float(((unsigned)u) << 16);
}

// ---- dtype detect: scan low-half-bf16 of first 256 words of x ----
__global__ __launch_bounds__(64) void detect_kernel(const unsigned* __restrict__ xw, int* __restrict__ flag) {
    int t = threadIdx.x;
    int hits = 0;
#pragma unroll
    for (int q = 0; q < 4; q++) {
        unsigned w = xw[t * 4 + q];
        float lo = __uint_as_float(w << 16);
        if (!(fabsf(lo) < 1e4f)) hits++;
    }
#pragma unroll
    for (int o = 32; o > 0; o >>= 1) hits += __shfl_xor(hits, o);
    if (t == 0) flag[0] = (hits > 8) ? 1 : 0;   // 1 => inputs are fp32
}

// ---- histogram of dst ----
__global__ __launch_bounds__(256) void count_kernel(const int* __restrict__ dst, int* __restrict__ cnt) {
    int e = blockIdx.x * 256 + threadIdx.x;
    if (e < EE) atomicAdd(&cnt[dst[e]], 1);
}

// ---- hierarchical scan stage 1 ----
__global__ __launch_bounds__(256) void scan1_kernel(
    const int* __restrict__ cnt, int* __restrict__ off, int* __restrict__ bsum)
{
    __shared__ int sd[256];
    int t = threadIdx.x;
    int i = blockIdx.x * 256 + t;
    int v = (i < NN) ? cnt[i] : 0;
    sd[t] = v;
    __syncthreads();
    for (int d = 1; d < 256; d <<= 1) {
        int u = (t >= d) ? sd[t - d] : 0;
        __syncthreads();
        sd[t] += u;
        __syncthreads();
    }
    if (i < NN) off[i] = sd[t] - v;
    if (t == 255) bsum[blockIdx.x] = sd[255];
}

// ---- stage 2: scan block sums ----
__global__ __launch_bounds__(256) void scan2_kernel(const int* __restrict__ bsum, int* __restrict__ boff) {
    __shared__ int sd[256];
    int t = threadIdx.x;
    int v = (t < SB) ? bsum[t] : 0;
    sd[t] = v;
    __syncthreads();
    for (int d = 1; d < 256; d <<= 1) {
        int u = (t >= d) ? sd[t - d] : 0;
        __syncthreads();
        sd[t] += u;
        __syncthreads();
    }
    if (t < SB) boff[t] = sd[t] - v;
}

// ---- stage 3: add block offsets + dinv ----
__global__ __launch_bounds__(256) void scan3_kernel(
    const int* __restrict__ cnt, int* __restrict__ off,
    const int* __restrict__ boff, float* __restrict__ dinv)
{
    int i = blockIdx.x * 256 + threadIdx.x;
    if (i < NN) {
        off[i] += boff[blockIdx.x];
        dinv[i] = rsqrtf((float)cnt[i] + 1.0f);
    }
    if (i == NN) off[NN] = EE;
}

// ---- placement ----
__global__ __launch_bounds__(256) void place_kernel(
    const int* __restrict__ src, const int* __restrict__ dst,
    const int* __restrict__ off, int* __restrict__ cur, int* __restrict__ csr_src)
{
    int e = blockIdx.x * 256 + threadIdx.x;
    if (e >= EE) return;
    int d = dst[e];
    int p = off[d] + atomicAdd(&cur[d], 1);
    csr_src[p] = src[e];
}

// ---- layer1 linear: A = (x@W1)*dinv, B = x@Wl1 + bl1 (interleaved LDS) ----
__global__ __launch_bounds__(256) void lin1_kernel(
    const void* __restrict__ xp, const void* __restrict__ W1p,
    const void* __restrict__ Wl1p, const void* __restrict__ bl1p,
    const float* __restrict__ dinv, const int* __restrict__ flagp,
    float* __restrict__ A, float* __restrict__ B)
{
    __shared__ float2 sWL[INF_ * HH];   // .x = W1, .y = Wl1
    __shared__ float sb[HH];
    const int flag = flagp[0];
    if (flag) {
        for (int t = threadIdx.x; t < INF_ * HH; t += 256)
            sWL[t] = make_float2(((const float*)W1p)[t], ((const float*)Wl1p)[t]);
        if (threadIdx.x < HH) sb[threadIdx.x] = ((const float*)bl1p)[threadIdx.x];
    } else {
        for (int t = threadIdx.x; t < INF_ * HH; t += 256)
            sWL[t] = make_float2(bfu2f(((const unsigned short*)W1p)[t]),
                                 bfu2f(((const unsigned short*)Wl1p)[t]));
        if (threadIdx.x < HH) sb[threadIdx.x] = bfu2f(((const unsigned short*)bl1p)[threadIdx.x]);
    }
    __syncthreads();

    int i = blockIdx.x * 256 + threadIdx.x;
    if (i >= NN) return;

    float a[HH], l[HH];
#pragma unroll
    for (int f = 0; f < HH; f++) { a[f] = 0.f; l[f] = 0.f; }

    for (int k0 = 0; k0 < INF_ / 8; k0++) {
        float xv[8];
        if (flag) {
            const float4* xr = (const float4*)((const float*)xp + (size_t)i * INF_);
            float4 r0 = xr[k0 * 2], r1 = xr[k0 * 2 + 1];
            xv[0] = r0.x; xv[1] = r0.y; xv[2] = r0.z; xv[3] = r0.w;
            xv[4] = r1.x; xv[5] = r1.y; xv[6] = r1.z; xv[7] = r1.w;
        } else {
            const uint4* xr = (const uint4*)((const unsigned short*)xp + (size_t)i * INF_);
            uint4 v = xr[k0];
            unsigned uu[4] = { v.x, v.y, v.z, v.w };
#pragma unroll
            for (int q = 0; q < 4; q++) {
                xv[q * 2]     = __uint_as_float(uu[q] << 16);
                xv[q * 2 + 1] = __uint_as_float(uu[q] & 0xffff0000u);
            }
        }
#pragma unroll
        for (int j = 0; j < 8; j++) {
            float xj = xv[j];
            int k = k0 * 8 + j;
#pragma unroll
            for (int f = 0; f < HH; f++) {
                float2 wv = sWL[k * HH + f];
                a[f] = fmaf(xj, wv.x, a[f]);
                l[f] = fmaf(xj, wv.y, l[f]);
            }
        }
    }
    float di = dinv[i];
#pragma unroll
    for (int f = 0; f < HH; f++) {
        A[i * HH + f] = a[f] * di;
        B[i * HH + f] = l[f] + sb[f];
    }
}

// ---- fused gather + combine, 16-edge-parallel.
// Wave layout: lane = e*4 + q; 4-lane group q loads float4 (16B) of neighbor row e.
// mode 0: Y[i] = relu(di*(agg + X[i]) + b) + Y[i]
// mode 1: Y[i] = (relu(di*(agg + X[i]) + b) + Y[i]) * di
// mode 2: Y[i] = di*(agg + X[i])
__global__ __launch_bounds__(256) void gather_combine_kernel(
    const int* __restrict__ off, const int* __restrict__ csr,
    const float* __restrict__ dinv, const float* __restrict__ X,
    float* __restrict__ Y, const void* __restrict__ bias,
    const int* __restrict__ flagp, int mode)
{
    int wid = (blockIdx.x * 256 + threadIdx.x) >> 6;   // node id
    int lane = threadIdx.x & 63;
    if (wid >= NN) return;
    int e = lane >> 2, q = lane & 3;
    int s0 = off[wid], s1 = off[wid + 1];
    float4 acc = make_float4(0.f, 0.f, 0.f, 0.f);
    for (int base = s0; base < s1; base += 16) {
        int p = base + e;
        bool valid = (p < s1);
        int s = valid ? csr[p] : 0;                        // 16 lanes-groups, broadcast x4
        float4 v = ((const float4*)X)[(size_t)s * 4 + q];  // 16B of 64B row
        if (valid) { acc.x += v.x; acc.y += v.y; acc.z += v.z; acc.w += v.w; }
    }
#pragma unroll
    for (int m = 4; m <= 32; m <<= 1) {
        acc.x += __shfl_xor(acc.x, m);
        acc.y += __shfl_xor(acc.y, m);
        acc.z += __shfl_xor(acc.z, m);
        acc.w += __shfl_xor(acc.w, m);
    }
    if (lane < 4) {    // lane == q: handles features q*4 .. q*4+3
        float di = dinv[wid];
        float4 xr = ((const float4*)X)[(size_t)wid * 4 + lane];
        float4 r;
        if (mode == 2) {
            r.x = di * (acc.x + xr.x);
            r.y = di * (acc.y + xr.y);
            r.z = di * (acc.z + xr.z);
            r.w = di * (acc.w + xr.w);
        } else {
            float4 yr = ((const float4*)Y)[(size_t)wid * 4 + lane];
            float bb[4];
#pragma unroll
            for (int c = 0; c < 4; c++)
                bb[c] = flagp[0] ? ((const float*)bias)[lane * 4 + c]
                                 : bfu2f(((const unsigned short*)bias)[lane * 4 + c]);
            float o0 = fmaxf(di * (acc.x + xr.x) + bb[0], 0.f) + yr.x;
            float o1 = fmaxf(di * (acc.y + xr.y) + bb[1], 0.f) + yr.y;
            float o2 = fmaxf(di * (acc.z + xr.z) + bb[2], 0.f) + yr.z;
            float o3 = fmaxf(di * (acc.w + xr.w) + bb[3], 0.f) + yr.w;
            if (mode) { o0 *= di; o1 *= di; o2 *= di; o3 *= di; }
            r = make_float4(o0, o1, o2, o3);
        }
        ((float4*)Y)[(size_t)wid * 4 + lane] = r;
    }
}

// ---- layer2 linear: reads h1 from B; A = (h1@W2)*dinv, B = h1@Wl2 + bl2 ----
__global__ __launch_bounds__(256) void lin2_kernel(
    float* __restrict__ B, const void* __restrict__ W2p,
    const void* __restrict__ Wl2p, const void* __restrict__ bl2p,
    const float* __restrict__ dinv, const int* __restrict__ flagp,
    float* __restrict__ A)
{
    __shared__ float2 sWL[HH * HH];
    __shared__ float sb[HH];
    const int flag = flagp[0];
    if (flag) {
        for (int t = threadIdx.x; t < HH * HH; t += 256)
            sWL[t] = make_float2(((const float*)W2p)[t], ((const float*)Wl2p)[t]);
        if (threadIdx.x < HH) sb[threadIdx.x] = ((const float*)bl2p)[threadIdx.x];
    } else {
        for (int t = threadIdx.x; t < HH * HH; t += 256)
            sWL[t] = make_float2(bfu2f(((const unsigned short*)W2p)[t]),
                                 bfu2f(((const unsigned short*)Wl2p)[t]));
        if (threadIdx.x < HH) sb[threadIdx.x] = bfu2f(((const unsigned short*)bl2p)[threadIdx.x]);
    }
    __syncthreads();

    int i = blockIdx.x * 256 + threadIdx.x;
    if (i >= NN) return;

    float z[HH];
    const float4* dr = (const float4*)(B + (size_t)i * HH);
#pragma unroll
    for (int q = 0; q < 4; q++) {
        float4 r = dr[q];
        z[q * 4 + 0] = r.x; z[q * 4 + 1] = r.y; z[q * 4 + 2] = r.z; z[q * 4 + 3] = r.w;
    }
    float a[HH], l[HH];
#pragma unroll
    for (int f = 0; f < HH; f++) { a[f] = 0.f; l[f] = 0.f; }
#pragma unroll
    for (int k = 0; k < HH; k++) {
        float zk = z[k];
#pragma unroll
        for (int f = 0; f < HH; f++) {
            float2 wv = sWL[k * HH + f];
            a[f] = fmaf(zk, wv.x, a[f]);
            l[f] = fmaf(zk, wv.y, l[f]);
        }
    }
    float di = dinv[i];
#pragma unroll
    for (int f = 0; f < HH; f++) {
        A[i * HH + f] = a[f] * di;
        B[i * HH + f] = l[f] + sb[f];
    }
}

// ---- final (streaming): z rows precomputed; y = z@Wo + bo, log_softmax ----
__global__ __launch_bounds__(256) void final_kernel(
    const float* __restrict__ Z, const void* __restrict__ Wop,
    const void* __restrict__ bop, const int* __restrict__ flagp, void* __restrict__ outp)
{
    __shared__ float sW[HH * OUTC];   // 19.2 KB
    __shared__ float sbb[OUTC];
    const int flag = flagp[0];
    if (flag) {
        for (int t = threadIdx.x; t < HH * OUTC; t += 256) sW[t] = ((const float*)Wop)[t];
        for (int t = threadIdx.x; t < OUTC; t += 256)      sbb[t] = ((const float*)bop)[t];
    } else {
        for (int t = threadIdx.x; t < HH * OUTC; t += 256) sW[t] = bfu2f(((const unsigned short*)Wop)[t]);
        for (int t = threadIdx.x; t < OUTC; t += 256)      sbb[t] = bfu2f(((const unsigned short*)bop)[t]);
    }
    __syncthreads();

    int wave = threadIdx.x >> 6, lane = threadIdx.x & 63;

    for (int it = 0; it < 4; it++) {
        int i = blockIdx.x * 16 + wave * 4 + it;     // 16 nodes per block
        if (i >= NN) continue;
        float zf = Z[(size_t)i * HH + (lane & 15)];  // lanes 0..15 hold the row
        float z[HH];
#pragma unroll
        for (int k = 0; k < HH; k++) z[k] = __shfl(zf, k);

        float y[5];
        float m = -1e30f;
#pragma unroll
        for (int jj = 0; jj < 5; jj++) {
            int j = lane + jj * 64;
            float a2 = 0.f;
            if (j < OUTC) {
                a2 = sbb[j];
#pragma unroll
                for (int k = 0; k < HH; k++) a2 = fmaf(z[k], sW[k * OUTC + j], a2);
                m = fmaxf(m, a2);
            }
            y[jj] = a2;
        }
#pragma unroll
        for (int o = 32; o > 0; o >>= 1) m = fmaxf(m, __shfl_xor(m, o));
        float s = 0.f;
#pragma unroll
        for (int jj = 0; jj < 5; jj++) {
            int j = lane + jj * 64;
            if (j < OUTC) s += __expf(y[jj] - m);
        }
#pragma unroll
        for (int o = 32; o > 0; o >>= 1) s += __shfl_xor(s, o);
        float lse = m + __logf(s);
#pragma unroll
        for (int jj = 0; jj < 5; jj++) {
            int j = lane + jj * 64;
            if (j < OUTC) {
                float v = y[jj] - lse;
                size_t ofs = (size_t)i * OUTC + j;
                if (flag) ((float*)outp)[ofs] = v;
                else      ((__hip_bfloat16*)outp)[ofs] = __float2bfloat16(v);
            }
        }
    }
}

extern "C" void kernel_launch(void* const* d_in, const int* in_sizes, int n_in,
                              void* d_out, int out_size, void* d_ws, size_t ws_size,
                              hipStream_t stream) {
    const void* x   = d_in[0];
    const int*  ei  = (const int*)d_in[1];
    const void* W1  = d_in[2];
    const void* b1  = d_in[3];
    const void* Wl1 = d_in[4];
    const void* bl1 = d_in[5];
    const void* W2  = d_in[6];
    const void* b2  = d_in[7];
    const void* Wl2 = d_in[8];
    const void* bl2 = d_in[9];
    const void* Wo  = d_in[10];
    const void* bo  = d_in[11];

    const int* srcp = ei;        // edge_index[0]
    const int* dstp = ei + EE;   // edge_index[1]

    // ws layout (4-byte words), 16B-aligned regions:
    char* wsb = (char*)d_ws;
    int*   flag    = (int*)wsb;                       // [0..3]
    int*   cnt     = (int*)(wsb + 4 * 4);             // 4 .. 50003
    int*   off     = (int*)(wsb + 4 * 50004);         // 50004 .. 100004
    int*   bsum    = (int*)(wsb + 4 * 100008);        // 100008 .. 100203
    int*   boff    = (int*)(wsb + 4 * 100264);        // 100264 .. 100459
    int*   csr_src = (int*)(wsb + 4 * 100520);        // 100520 .. 900519
    float* dinv    = (float*)(wsb + 4 * 900520);      // 900520 .. 950519
    float* A       = (float*)(wsb + 4 * 950520);      // .. 1750519
    float* B       = (float*)(wsb + 4 * 1750520);     // .. 2550519  (~10.2 MB)

    const int gE = (EE + 255) / 256;
    const int gN = (NN + 255) / 256;
    const int gG = (NN * 64 + 255) / 256;   // wave-per-node gathers

    // dtype detect
    detect_kernel<<<1, 64, 0, stream>>>((const unsigned*)x, flag);

    // CSR build + dinv (hierarchical scan)
    hipMemsetAsync(cnt, 0, NN * sizeof(int), stream);
    count_kernel<<<gE, 256, 0, stream>>>(dstp, cnt);
    scan1_kernel<<<SB, 256, 0, stream>>>(cnt, off, bsum);
    scan2_kernel<<<1, 256, 0, stream>>>(bsum, boff);
    scan3_kernel<<<SB, 256, 0, stream>>>(cnt, off, boff, dinv);
    hipMemsetAsync(cnt, 0, NN * sizeof(int), stream);   // reuse cnt as cursor
    place_kernel<<<gE, 256, 0, stream>>>(srcp, dstp, off, cnt, csr_src);

    // layer 1: lin -> gather+combine (B <- h1)
    lin1_kernel<<<gN, 256, 0, stream>>>(x, W1, Wl1, bl1, dinv, flag, A, B);
    gather_combine_kernel<<<gG, 256, 0, stream>>>(off, csr_src, dinv, A, B, b1, flag, 0);

    // layer 2: lin -> gather+combine (B <- out2*dinv)
    lin2_kernel<<<gN, 256, 0, stream>>>(B, W2, Wl2, bl2, dinv, flag, A);
    gather_combine_kernel<<<gG, 256, 0, stream>>>(off, csr_src, dinv, A, B, b2, flag, 1);

    // output aggregation: A <- z = dinv*(agg(B) + B)
    gather_combine_kernel<<<gG, 256, 0, stream>>>(off, csr_src, dinv, B, A, b2, flag, 2);

    // final matmul + log_softmax (streaming)
    final_kernel<<<(NN + 15) / 16, 256, 0, stream>>>(A, Wo, bo, flag, d_out);
}